// Round 2
// baseline (2888.907 us; speedup 1.0000x reference)
//
#include <hip/hip_runtime.h>

typedef _Float16 half8 __attribute__((ext_vector_type(8)));
typedef _Float16 half4 __attribute__((ext_vector_type(4)));
typedef float floatx4 __attribute__((ext_vector_type(4)));

#define T_STEPS 20
#define NSEQ 131072
#define HID 192
#define ROWS 64
#define HPAD 200          // fp16 elems per LDS h-row (400 B stride)
#define WOUT_OFF 147456   // fp16 elems: whh frags [12 ht][6 kc][4 g][64 lane][8]

__device__ __forceinline__ float fsig(float x) {
    return __builtin_amdgcn_rcpf(1.f + __builtin_amdgcn_exp2f(-1.4426950408889634f * x));
}
__device__ __forceinline__ float ftanh(float x) {
    return 1.f - 2.f * __builtin_amdgcn_rcpf(__builtin_amdgcn_exp2f(2.8853900817779268f * x) + 1.f);
}

// Prologue: rewrite w_hh / w_out into MFMA B-fragment order (fp16).
// B-frag for 16x16x32: lane L = q*16 + n holds k = q*8 .. q*8+7 of column n.
__global__ void build_frags(const float* __restrict__ whh,
                            const float* __restrict__ wout,
                            _Float16* __restrict__ dst) {
    int i = blockIdx.x * 256 + threadIdx.x;
    if (i < WOUT_OFF) {
        int e = i & 7, L = (i >> 3) & 63, blk = i >> 9;   // blk = (ht*6+kc)*4+g
        int g = blk & 3, kc = (blk >> 2) % 6, ht = blk / 24;
        int n = L & 15, q = L >> 4;
        dst[i] = (_Float16)whh[(size_t)(g * HID + ht * 16 + n) * HID + kc * 32 + q * 8 + e];
    } else if (i < WOUT_OFF + 3072) {                     // w_out frags [6 kc][64][8]
        int j = i - WOUT_OFF;
        int e = j & 7, L = (j >> 3) & 63, kc = j >> 9;
        int n = L & 15, q = L >> 4;
        dst[i] = (_Float16)((n < 2) ? wout[n * HID + kc * 32 + q * 8 + e] : 0.f);
    }
}

__global__ __launch_bounds__(768) void lstm_fused_kernel(
    const float* __restrict__ obs,       // [20][N][2]
    const float* __restrict__ h0,        // [N][192]
    const float* __restrict__ w_ih,      // [768][2]
    const float* __restrict__ b_ih,      // [768]
    const float* __restrict__ b_hh,      // [768]
    const float* __restrict__ b_out,     // [2]
    const _Float16* __restrict__ frags,  // whh + wout fragments (fp16)
    float* __restrict__ out)             // [20][N][2]
{
    __shared__ _Float16 hbuf[2][ROWS][HPAD];     // 51200 B, double-buffered h
    __shared__ float x_all[T_STEPS][ROWS][2];    // 10240 B, all steps' x
    __shared__ float wih0[4 * HID], wih1[4 * HID], bsum[4 * HID];

    const int tid  = threadIdx.x;
    const int wave = tid >> 6;       // 0..11 = hidden tile
    const int lane = tid & 63;
    const int quad = lane >> 4;
    const int l16  = lane & 15;
    const int ht   = wave;
    const int base = blockIdx.x * ROWS;

    // ---- staging ----
    for (int i = tid; i < 4 * HID; i += 768) {
        wih0[i] = w_ih[2 * i];
        wih1[i] = w_ih[2 * i + 1];
        bsum[i] = b_ih[i] + b_hh[i];
    }
    for (int i = tid; i < T_STEPS * ROWS * 2; i += 768) {
        int t = i / (ROWS * 2), rr = i - t * (ROWS * 2);
        int src = (t == 0) ? 0 : (t - 1);
        x_all[t][rr >> 1][rr & 1] = obs[(size_t)src * NSEQ * 2 + (size_t)base * 2 + rr];
    }
    // h0 -> hbuf[0], vectorized
    for (int i = tid; i < ROWS * HID / 4; i += 768) {
        float4 v = *(const float4*)&h0[(size_t)base * HID + i * 4];
        int row = (i * 4) / HID, k = (i * 4) - row * HID;
        half4 h = {(_Float16)v.x, (_Float16)v.y, (_Float16)v.z, (_Float16)v.w};
        *(half4*)&hbuf[0][row][k] = h;
    }
    const float bo_n = (l16 < 2) ? b_out[l16] : 0.f;  // for out-MFMA bias init

    float c[16];
#pragma unroll
    for (int i = 0; i < 16; ++i) c[i] = 0.f;

    const _Float16* bptr = frags + ht * (24 * 512);   // this wave's 24 KB region
    const _Float16* wof  = frags + WOUT_OFF;
    const int j = ht * 16 + l16;

    __syncthreads();

    for (int t = 0; t < T_STEPS; ++t) {
        const _Float16* hb = &hbuf[t & 1][0][0];
        _Float16*       hn = &hbuf[(t + 1) & 1][0][0];

        // ---- gate MFMA: wave ht owns cols {g*192 + ht*16 + 0..15} ----
        floatx4 acc[4][4];
#pragma unroll
        for (int rt = 0; rt < 4; ++rt)
#pragma unroll
            for (int g = 0; g < 4; ++g)
                acc[rt][g] = (floatx4){0.f, 0.f, 0.f, 0.f};

#pragma unroll
        for (int kc = 0; kc < 6; ++kc) {
            half8 a[4];
#pragma unroll
            for (int rt = 0; rt < 4; ++rt)
                a[rt] = *(const half8*)(hb + (rt * 16 + l16) * HPAD + kc * 32 + quad * 8);
#pragma unroll
            for (int g = 0; g < 4; ++g) {
                half8 b = *(const half8*)(bptr + (kc * 4 + g) * 512 + lane * 8);
#pragma unroll
                for (int rt = 0; rt < 4; ++rt)
                    acc[rt][g] = __builtin_amdgcn_mfma_f32_16x16x32_f16(a[rt], b, acc[rt][g], 0, 0, 0);
            }
        }

        // ---- out_{t-1} = h_t @ w_out.T + b_out via MFMA (wave 0 only) ----
        if (ht == 0 && t > 0) {
            const int ot = t - 1;
#pragma unroll
            for (int rt = 0; rt < 4; ++rt) {
                floatx4 ao = {bo_n, bo_n, bo_n, bo_n};
#pragma unroll
                for (int kc = 0; kc < 6; ++kc) {
                    half8 a = *(const half8*)(hb + (rt * 16 + l16) * HPAD + kc * 32 + quad * 8);
                    half8 b = *(const half8*)(wof + kc * 512 + lane * 8);
                    ao = __builtin_amdgcn_mfma_f32_16x16x32_f16(a, b, ao, 0, 0, 0);
                }
                if (l16 < 2) {
#pragma unroll
                    for (int r = 0; r < 4; ++r)
                        out[((size_t)ot * NSEQ + base + rt * 16 + quad * 4 + r) * 2 + l16] = ao[r];
                }
            }
        }

        // ---- activation (wave-local: i/f/g/o for unit j live in this wave) ----
        float bs[4], w0[4], w1[4];
#pragma unroll
        for (int g = 0; g < 4; ++g) {
            bs[g] = bsum[g * HID + j];
            w0[g] = wih0[g * HID + j];
            w1[g] = wih1[g * HID + j];
        }
#pragma unroll
        for (int rt = 0; rt < 4; ++rt) {
#pragma unroll
            for (int r = 0; r < 4; ++r) {
                const int row = rt * 16 + quad * 4 + r;
                const float x0 = x_all[t][row][0], x1 = x_all[t][row][1];
                const float gi = acc[rt][0][r] + bs[0] + x0 * w0[0] + x1 * w1[0];
                const float gf = acc[rt][1][r] + bs[1] + x0 * w0[1] + x1 * w1[1];
                const float gg = acc[rt][2][r] + bs[2] + x0 * w0[2] + x1 * w1[2];
                const float go = acc[rt][3][r] + bs[3] + x0 * w0[3] + x1 * w1[3];
                const int ci = rt * 4 + r;
                const float cn = fsig(gf) * c[ci] + fsig(gi) * ftanh(gg);
                c[ci] = cn;
                hn[row * HPAD + j] = (_Float16)(fsig(go) * ftanh(cn));
            }
        }
        __syncthreads();   // h_{t+1} complete; next step reads it, writes hbuf[t&1]
    }

    // ---- out_19 from h_20 (in hbuf[0]) ----
    if (ht == 0) {
        const _Float16* hb = &hbuf[0][0][0];
#pragma unroll
        for (int rt = 0; rt < 4; ++rt) {
            floatx4 ao = {bo_n, bo_n, bo_n, bo_n};
#pragma unroll
            for (int kc = 0; kc < 6; ++kc) {
                half8 a = *(const half8*)(hb + (rt * 16 + l16) * HPAD + kc * 32 + quad * 8);
                half8 b = *(const half8*)(wof + kc * 512 + lane * 8);
                ao = __builtin_amdgcn_mfma_f32_16x16x32_f16(a, b, ao, 0, 0, 0);
            }
            if (l16 < 2) {
#pragma unroll
                for (int r = 0; r < 4; ++r)
                    out[((size_t)19 * NSEQ + base + rt * 16 + quad * 4 + r) * 2 + l16] = ao[r];
            }
        }
    }
}

extern "C" void kernel_launch(void* const* d_in, const int* in_sizes, int n_in,
                              void* d_out, int out_size, void* d_ws, size_t ws_size,
                              hipStream_t stream) {
    const float* obs  = (const float*)d_in[0];
    const float* h0   = (const float*)d_in[1];
    const float* wih  = (const float*)d_in[2];
    const float* whh  = (const float*)d_in[3];
    const float* bih  = (const float*)d_in[4];
    const float* bhh  = (const float*)d_in[5];
    const float* wout = (const float*)d_in[6];
    const float* bout = (const float*)d_in[7];
    float* out = (float*)d_out;
    _Float16* frags = (_Float16*)d_ws;   // 301056 B used

    build_frags<<<(WOUT_OFF + 3072) / 256, 256, 0, stream>>>(whh, wout, frags);
    lstm_fused_kernel<<<NSEQ / ROWS, 768, 0, stream>>>(
        obs, h0, wih, bih, bhh, bout, frags, out);
}

// Round 3
// 2675.529 us; speedup vs baseline: 1.0798x; 1.0798x over previous
//
#include <hip/hip_runtime.h>

typedef _Float16 half8 __attribute__((ext_vector_type(8)));
typedef float floatx4 __attribute__((ext_vector_type(4)));

#define T_STEPS 20
#define NSEQ 131072
#define HID 192
#define ROWS 64
#define HPAD 200            // fp16 elems per LDS h-row (400 B stride)
#define REGA_SZ 49152       // kc 0..1 frags  [12ht][2kc][4g][64][8]  -> LDS
#define REGB_SZ 98304       // kc 2..5 frags  [12ht][4kc2][4g][64][8] -> registers
#define REGW_OFF (REGA_SZ + REGB_SZ)   // wout frags [6kc][64][8]

__device__ __forceinline__ float fsig(float x) {
    return __builtin_amdgcn_rcpf(1.f + __builtin_amdgcn_exp2f(-1.4426950408889634f * x));
}
__device__ __forceinline__ float ftanh(float x) {
    return 1.f - 2.f * __builtin_amdgcn_rcpf(__builtin_amdgcn_exp2f(2.8853900817779268f * x) + 1.f);
}

// Rewrite w_hh / w_out into MFMA B-fragment order (fp16).
// B-frag 16x16x32: lane L = q*16 + n holds k = q*8..q*8+7 of column n.
__global__ void build_frags(const float* __restrict__ whh,
                            const float* __restrict__ wout,
                            _Float16* __restrict__ dst) {
    int i = blockIdx.x * 256 + threadIdx.x;
    if (i < REGA_SZ) {
        int e = i & 7, L = (i >> 3) & 63, g = (i >> 9) & 3, kc = (i >> 11) & 1, ht = i >> 12;
        int n = L & 15, q = L >> 4;
        dst[i] = (_Float16)whh[(size_t)(g * HID + ht * 16 + n) * HID + kc * 32 + q * 8 + e];
    } else if (i < REGW_OFF) {
        int j = i - REGA_SZ;
        int e = j & 7, L = (j >> 3) & 63, g = (j >> 9) & 3, kc2 = (j >> 11) & 3, ht = j >> 13;
        int n = L & 15, q = L >> 4;
        dst[i] = (_Float16)whh[(size_t)(g * HID + ht * 16 + n) * HID + (kc2 + 2) * 32 + q * 8 + e];
    } else if (i < REGW_OFF + 3072) {
        int k = i - REGW_OFF;
        int e = k & 7, L = (k >> 3) & 63, kc = k >> 9;
        int n = L & 15, q = L >> 4;
        dst[i] = (_Float16)((n < 2) ? wout[n * HID + kc * 32 + q * 8 + e] : 0.f);
    }
}

__global__ __launch_bounds__(768, 3) void lstm_fused_kernel(
    const float* __restrict__ obs,       // [20][N][2]
    const float* __restrict__ h0,        // [N][192]
    const float* __restrict__ w_ih,      // [768][2]
    const float* __restrict__ b_ih,      // [768]
    const float* __restrict__ b_hh,      // [768]
    const float* __restrict__ b_out,     // [2]
    const _Float16* __restrict__ frags,  // whh + wout fragments (fp16)
    float* __restrict__ out)             // [20][N][2]
{
    __shared__ _Float16 b_lds[REGA_SZ];          // 98304 B: whh kc 0..1
    __shared__ _Float16 h_lds[ROWS][HPAD];       // 25600 B: h, single-buffered
    __shared__ _Float16 wo_lds[3072];            //  6144 B: wout frags
    __shared__ float wih0[4 * HID], wih1[4 * HID], bsum[4 * HID];  // 9216 B
    __shared__ float2 x_s[2][ROWS];              //  1024 B: x, 1-step-ahead

    const int tid  = threadIdx.x;
    const int wave = tid >> 6;       // 0..11 = hidden-col tile
    const int lane = tid & 63;
    const int quad = lane >> 4;
    const int l16  = lane & 15;
    const int ht   = wave;
    const int base = blockIdx.x * ROWS;

    // ---- one-time staging ----
    for (int i = tid; i < REGA_SZ / 8; i += 768)
        *(half8*)&b_lds[i * 8] = *(const half8*)&frags[i * 8];
    if (tid < 384)
        *(half8*)&wo_lds[tid * 8] = *(const half8*)&frags[REGW_OFF + tid * 8];
    for (int i = tid; i < 4 * HID; i += 768) {
        wih0[i] = w_ih[2 * i];
        wih1[i] = w_ih[2 * i + 1];
        bsum[i] = b_ih[i] + b_hh[i];
    }
    for (int i = tid; i < ROWS * HID / 4; i += 768) {
        float4 v = *(const float4*)&h0[(size_t)base * HID + i * 4];
        int row = (i * 4) / HID, k = (i * 4) - row * HID;
        h_lds[row][k]     = (_Float16)v.x;
        h_lds[row][k + 1] = (_Float16)v.y;
        h_lds[row][k + 2] = (_Float16)v.z;
        h_lds[row][k + 3] = (_Float16)v.w;
    }
    if (tid < ROWS)   // x for t=0 (src row 0)
        x_s[0][tid] = *(const float2*)&obs[((size_t)base + tid) * 2];

    // ---- per-wave register-resident B fragments (kc 2..5), loaded once ----
    half8 breg[16];
    {
        const _Float16* p = frags + REGA_SZ + ht * 8192 + lane * 8;
#pragma unroll
        for (int q = 0; q < 16; ++q)
            breg[q] = *(const half8*)(p + q * 512);
    }
    const float bo_n = (l16 < 2) ? b_out[l16] : 0.f;

    float c[16];
#pragma unroll
    for (int i = 0; i < 16; ++i) c[i] = 0.f;

    __syncthreads();

    for (int t = 0; t < T_STEPS; ++t) {
        // ================= gate MFMA phase (reads h_t) =================
        floatx4 acc[4][4];
#pragma unroll
        for (int rt = 0; rt < 4; ++rt)
#pragma unroll
            for (int g = 0; g < 4; ++g)
                acc[rt][g] = (floatx4){0.f, 0.f, 0.f, 0.f};

#pragma unroll
        for (int kc = 0; kc < 2; ++kc) {
            half8 bt[4];
#pragma unroll
            for (int g = 0; g < 4; ++g)
                bt[g] = *(const half8*)&b_lds[((ht * 2 + kc) * 4 + g) * 512 + lane * 8];
#pragma unroll
            for (int rt = 0; rt < 4; ++rt) {
                half8 a = *(const half8*)&h_lds[rt * 16 + l16][kc * 32 + quad * 8];
#pragma unroll
                for (int g = 0; g < 4; ++g)
                    acc[rt][g] = __builtin_amdgcn_mfma_f32_16x16x32_f16(a, bt[g], acc[rt][g], 0, 0, 0);
            }
        }
#pragma unroll
        for (int kc2 = 0; kc2 < 4; ++kc2) {
#pragma unroll
            for (int rt = 0; rt < 4; ++rt) {
                half8 a = *(const half8*)&h_lds[rt * 16 + l16][(kc2 + 2) * 32 + quad * 8];
#pragma unroll
                for (int g = 0; g < 4; ++g)
                    acc[rt][g] = __builtin_amdgcn_mfma_f32_16x16x32_f16(a, breg[kc2 * 4 + g], acc[rt][g], 0, 0, 0);
            }
        }

        // ---- out_{t-1} = h_t @ w_out.T + b_out (wave 0, reads h_t) ----
        if (ht == 0 && t > 0) {
            const int ot = t - 1;
#pragma unroll
            for (int rt = 0; rt < 4; ++rt) {
                floatx4 ao = {bo_n, bo_n, bo_n, bo_n};
#pragma unroll
                for (int kc = 0; kc < 6; ++kc) {
                    half8 a = *(const half8*)&h_lds[rt * 16 + l16][kc * 32 + quad * 8];
                    half8 b = *(const half8*)&wo_lds[kc * 512 + lane * 8];
                    ao = __builtin_amdgcn_mfma_f32_16x16x32_f16(a, b, ao, 0, 0, 0);
                }
                if (l16 < 2) {
#pragma unroll
                    for (int r = 0; r < 4; ++r)
                        out[((size_t)ot * NSEQ + base + rt * 16 + quad * 4 + r) * 2 + l16] = ao[r];
                }
            }
        }

        __syncthreads();   // all h_t reads complete; safe to overwrite h

        // ================= activation phase (writes h_{t+1}) =================
        if (t < T_STEPS - 1 && tid < ROWS)   // stage x for step t+1 (src row t)
            x_s[(t + 1) & 1][tid] = *(const float2*)&obs[((size_t)t * NSEQ + base + tid) * 2];

        const int j = ht * 16 + l16;
        float bs[4], w0[4], w1[4];
#pragma unroll
        for (int g = 0; g < 4; ++g) {
            bs[g] = bsum[g * HID + j];
            w0[g] = wih0[g * HID + j];
            w1[g] = wih1[g * HID + j];
        }
#pragma unroll
        for (int rt = 0; rt < 4; ++rt) {
#pragma unroll
            for (int r = 0; r < 4; ++r) {
                const int row = rt * 16 + quad * 4 + r;
                const float2 xv = x_s[t & 1][row];
                const float gi = acc[rt][0][r] + bs[0] + xv.x * w0[0] + xv.y * w1[0];
                const float gf = acc[rt][1][r] + bs[1] + xv.x * w0[1] + xv.y * w1[1];
                const float gg = acc[rt][2][r] + bs[2] + xv.x * w0[2] + xv.y * w1[2];
                const float go = acc[rt][3][r] + bs[3] + xv.x * w0[3] + xv.y * w1[3];
                const int ci = rt * 4 + r;
                const float cn = fsig(gf) * c[ci] + fsig(gi) * ftanh(gg);
                c[ci] = cn;
                h_lds[row][j] = (_Float16)(fsig(go) * ftanh(cn));
            }
        }
        __syncthreads();   // h_{t+1} complete before next step's MFMA reads
    }

    // ---- out_19 from h_20 ----
    if (ht == 0) {
#pragma unroll
        for (int rt = 0; rt < 4; ++rt) {
            floatx4 ao = {bo_n, bo_n, bo_n, bo_n};
#pragma unroll
            for (int kc = 0; kc < 6; ++kc) {
                half8 a = *(const half8*)&h_lds[rt * 16 + l16][kc * 32 + quad * 8];
                half8 b = *(const half8*)&wo_lds[kc * 512 + lane * 8];
                ao = __builtin_amdgcn_mfma_f32_16x16x32_f16(a, b, ao, 0, 0, 0);
            }
            if (l16 < 2) {
#pragma unroll
                for (int r = 0; r < 4; ++r)
                    out[((size_t)19 * NSEQ + base + rt * 16 + quad * 4 + r) * 2 + l16] = ao[r];
            }
        }
    }
}

extern "C" void kernel_launch(void* const* d_in, const int* in_sizes, int n_in,
                              void* d_out, int out_size, void* d_ws, size_t ws_size,
                              hipStream_t stream) {
    const float* obs  = (const float*)d_in[0];
    const float* h0   = (const float*)d_in[1];
    const float* wih  = (const float*)d_in[2];
    const float* whh  = (const float*)d_in[3];
    const float* bih  = (const float*)d_in[4];
    const float* bhh  = (const float*)d_in[5];
    const float* wout = (const float*)d_in[6];
    const float* bout = (const float*)d_in[7];
    float* out = (float*)d_out;
    _Float16* frags = (_Float16*)d_ws;   // 301056 B used

    build_frags<<<(REGW_OFF + 3072 + 255) / 256, 256, 0, stream>>>(whh, wout, frags);
    lstm_fused_kernel<<<NSEQ / ROWS, 768, 0, stream>>>(
        obs, h0, wih, bih, bhh, bout, frags, out);
}

// Round 4
// 1684.257 us; speedup vs baseline: 1.7152x; 1.5886x over previous
//
#include <hip/hip_runtime.h>

typedef _Float16 half8 __attribute__((ext_vector_type(8)));
typedef float floatx4 __attribute__((ext_vector_type(4)));

#define T_STEPS 20
#define NSEQ 131072
#define HID 192
#define ROWS 32
#define HPAD 200            // fp16 elems per LDS h-row (400 B stride)
#define REGA_SZ 49152       // kc 0..1 frags  [12ht][2kc][4g][64][8]  -> LDS
#define REGB_SZ 98304       // kc 2..5 frags  [12ht][4kc2][4g][64][8] -> registers
#define REGW_OFF (REGA_SZ + REGB_SZ)   // wout frags [6kc][64][8]

__device__ __forceinline__ float fsig(float x) {
    return __builtin_amdgcn_rcpf(1.f + __builtin_amdgcn_exp2f(-1.4426950408889634f * x));
}
__device__ __forceinline__ float ftanh(float x) {
    return 1.f - 2.f * __builtin_amdgcn_rcpf(__builtin_amdgcn_exp2f(2.8853900817779268f * x) + 1.f);
}

// Rewrite w_hh / w_out into MFMA B-fragment order (fp16).
// B-frag 16x16x32: lane L = q*16 + n holds k = q*8..q*8+7 of column n.
__global__ void build_frags(const float* __restrict__ whh,
                            const float* __restrict__ wout,
                            _Float16* __restrict__ dst) {
    int i = blockIdx.x * 256 + threadIdx.x;
    if (i < REGA_SZ) {
        int e = i & 7, L = (i >> 3) & 63, g = (i >> 9) & 3, kc = (i >> 11) & 1, ht = i >> 12;
        int n = L & 15, q = L >> 4;
        dst[i] = (_Float16)whh[(size_t)(g * HID + ht * 16 + n) * HID + kc * 32 + q * 8 + e];
    } else if (i < REGW_OFF) {
        int j = i - REGA_SZ;
        int e = j & 7, L = (j >> 3) & 63, g = (j >> 9) & 3, kc2 = (j >> 11) & 3, ht = j >> 13;
        int n = L & 15, q = L >> 4;
        dst[i] = (_Float16)whh[(size_t)(g * HID + ht * 16 + n) * HID + (kc2 + 2) * 32 + q * 8 + e];
    } else if (i < REGW_OFF + 3072) {
        int k = i - REGW_OFF;
        int e = k & 7, L = (k >> 3) & 63, kc = k >> 9;
        int n = L & 15, q = L >> 4;
        dst[i] = (_Float16)((n < 2) ? wout[n * HID + kc * 32 + q * 8 + e] : 0.f);
    }
}

__global__ __launch_bounds__(768, 3) void lstm_fused_kernel(
    const float* __restrict__ obs,       // [20][N][2]
    const float* __restrict__ h0,        // [N][192]
    const float* __restrict__ w_ih,      // [768][2]
    const float* __restrict__ b_ih,      // [768]
    const float* __restrict__ b_hh,      // [768]
    const float* __restrict__ b_out,     // [2]
    const _Float16* __restrict__ frags,  // whh + wout fragments (fp16)
    float* __restrict__ out)             // [20][N][2]
{
    __shared__ _Float16 b_lds[REGA_SZ];          // 98304 B: whh kc 0..1
    __shared__ _Float16 hbuf[2][ROWS][HPAD];     // 25600 B: h double-buffered
    __shared__ _Float16 wo_lds[3072];            //  6144 B: wout frags
    __shared__ float wih0[4 * HID], wih1[4 * HID], bsum[4 * HID];  // 9216 B
    __shared__ float2 x_all[T_STEPS][ROWS];      //  5120 B: all steps' x

    const int tid  = threadIdx.x;
    const int wave = tid >> 6;       // 0..11 = hidden-col tile
    const int lane = tid & 63;
    const int quad = lane >> 4;
    const int l16  = lane & 15;
    const int ht   = wave;
    const int base = blockIdx.x * ROWS;

    // ---- one-time staging ----
    for (int i = tid; i < REGA_SZ / 8; i += 768)
        *(half8*)&b_lds[i * 8] = *(const half8*)&frags[i * 8];
    if (tid < 384)
        *(half8*)&wo_lds[tid * 8] = *(const half8*)&frags[REGW_OFF + tid * 8];
    for (int i = tid; i < 4 * HID; i += 768) {
        wih0[i] = w_ih[2 * i];
        wih1[i] = w_ih[2 * i + 1];
        bsum[i] = b_ih[i] + b_hh[i];
    }
    for (int i = tid; i < ROWS * HID / 4; i += 768) {
        float4 v = *(const float4*)&h0[(size_t)base * HID + i * 4];
        int row = (i * 4) / HID, k = (i * 4) - row * HID;
        hbuf[0][row][k]     = (_Float16)v.x;
        hbuf[0][row][k + 1] = (_Float16)v.y;
        hbuf[0][row][k + 2] = (_Float16)v.z;
        hbuf[0][row][k + 3] = (_Float16)v.w;
    }
    if (tid < T_STEPS * ROWS) {      // x for all steps, once
        int t = tid >> 5, r = tid & 31;
        int src = (t == 0) ? 0 : (t - 1);
        x_all[t][r] = *(const float2*)&obs[((size_t)src * NSEQ + base + r) * 2];
    }

    // ---- per-wave register-resident B fragments (kc 2..5): 64 VGPRs ----
    half8 breg[16];
    {
        const _Float16* p = frags + REGA_SZ + ht * 8192 + lane * 8;
#pragma unroll
        for (int q = 0; q < 16; ++q)
            breg[q] = *(const half8*)(p + q * 512);
    }
    const float bo_n = (l16 < 2) ? b_out[l16] : 0.f;

    float c[8];
#pragma unroll
    for (int i = 0; i < 8; ++i) c[i] = 0.f;

    const int j = ht * 16 + l16;
    float bs[4], w0[4], w1[4];
#pragma unroll
    for (int g = 0; g < 4; ++g) {
        bs[g] = b_ih[g * HID + j] + b_hh[g * HID + j];
        w0[g] = w_ih[(g * HID + j) * 2];
        w1[g] = w_ih[(g * HID + j) * 2 + 1];
    }

    __syncthreads();

    for (int t = 0; t < T_STEPS; ++t) {
        const _Float16* hb = &hbuf[t & 1][0][0];
        _Float16*       hn = &hbuf[(t + 1) & 1][0][0];

        // ================= gate MFMA phase (reads hbuf[t&1]) =================
        floatx4 acc[2][4];
#pragma unroll
        for (int rt = 0; rt < 2; ++rt)
#pragma unroll
            for (int g = 0; g < 4; ++g)
                acc[rt][g] = (floatx4){0.f, 0.f, 0.f, 0.f};

#pragma unroll
        for (int kc = 0; kc < 2; ++kc) {
            half8 bt[4];
#pragma unroll
            for (int g = 0; g < 4; ++g)
                bt[g] = *(const half8*)&b_lds[((ht * 2 + kc) * 4 + g) * 512 + lane * 8];
#pragma unroll
            for (int rt = 0; rt < 2; ++rt) {
                half8 a = *(const half8*)(hb + (rt * 16 + l16) * HPAD + kc * 32 + quad * 8);
#pragma unroll
                for (int g = 0; g < 4; ++g)
                    acc[rt][g] = __builtin_amdgcn_mfma_f32_16x16x32_f16(a, bt[g], acc[rt][g], 0, 0, 0);
            }
        }
#pragma unroll
        for (int kc2 = 0; kc2 < 4; ++kc2) {
#pragma unroll
            for (int rt = 0; rt < 2; ++rt) {
                half8 a = *(const half8*)(hb + (rt * 16 + l16) * HPAD + (kc2 + 2) * 32 + quad * 8);
#pragma unroll
                for (int g = 0; g < 4; ++g)
                    acc[rt][g] = __builtin_amdgcn_mfma_f32_16x16x32_f16(a, breg[kc2 * 4 + g], acc[rt][g], 0, 0, 0);
            }
        }

        // ---- out_{t-1} = h_t @ w_out.T + b_out (wave 0, also reads hbuf[t&1]) ----
        if (ht == 0 && t > 0) {
            const int ot = t - 1;
#pragma unroll
            for (int rt = 0; rt < 2; ++rt) {
                floatx4 ao = {bo_n, bo_n, bo_n, bo_n};
#pragma unroll
                for (int kc = 0; kc < 6; ++kc) {
                    half8 a = *(const half8*)(hb + (rt * 16 + l16) * HPAD + kc * 32 + quad * 8);
                    half8 b = *(const half8*)&wo_lds[kc * 512 + lane * 8];
                    ao = __builtin_amdgcn_mfma_f32_16x16x32_f16(a, b, ao, 0, 0, 0);
                }
                if (l16 < 2) {
#pragma unroll
                    for (int r = 0; r < 4; ++r)
                        out[((size_t)ot * NSEQ + base + rt * 16 + quad * 4 + r) * 2 + l16] = ao[r];
                }
            }
        }

        // ============ activation phase (writes hbuf[(t+1)&1]) ============
#pragma unroll
        for (int rt = 0; rt < 2; ++rt) {
#pragma unroll
            for (int r = 0; r < 4; ++r) {
                const int row = rt * 16 + quad * 4 + r;
                const float2 xv = x_all[t][row];
                const float gi = acc[rt][0][r] + bs[0] + xv.x * w0[0] + xv.y * w1[0];
                const float gf = acc[rt][1][r] + bs[1] + xv.x * w0[1] + xv.y * w1[1];
                const float gg = acc[rt][2][r] + bs[2] + xv.x * w0[2] + xv.y * w1[2];
                const float go = acc[rt][3][r] + bs[3] + xv.x * w0[3] + xv.y * w1[3];
                const int ci = rt * 4 + r;
                const float cn = fsig(gf) * c[ci] + fsig(gi) * ftanh(gg);
                c[ci] = cn;
                hn[row * HPAD + j] = (_Float16)(fsig(go) * ftanh(cn));
            }
        }
        __syncthreads();   // h_{t+1} done; all hbuf[t&1] reads done -> next step safe
    }

    // ---- out_19 from h_20 (in hbuf[0]) ----
    if (ht == 0) {
        const _Float16* hb = &hbuf[0][0][0];
#pragma unroll
        for (int rt = 0; rt < 2; ++rt) {
            floatx4 ao = {bo_n, bo_n, bo_n, bo_n};
#pragma unroll
            for (int kc = 0; kc < 6; ++kc) {
                half8 a = *(const half8*)(hb + (rt * 16 + l16) * HPAD + kc * 32 + quad * 8);
                half8 b = *(const half8*)&wo_lds[kc * 512 + lane * 8];
                ao = __builtin_amdgcn_mfma_f32_16x16x32_f16(a, b, ao, 0, 0, 0);
            }
            if (l16 < 2) {
#pragma unroll
                for (int r = 0; r < 4; ++r)
                    out[((size_t)19 * NSEQ + base + rt * 16 + quad * 4 + r) * 2 + l16] = ao[r];
            }
        }
    }
}

extern "C" void kernel_launch(void* const* d_in, const int* in_sizes, int n_in,
                              void* d_out, int out_size, void* d_ws, size_t ws_size,
                              hipStream_t stream) {
    const float* obs  = (const float*)d_in[0];
    const float* h0   = (const float*)d_in[1];
    const float* wih  = (const float*)d_in[2];
    const float* whh  = (const float*)d_in[3];
    const float* bih  = (const float*)d_in[4];
    const float* bhh  = (const float*)d_in[5];
    const float* wout = (const float*)d_in[6];
    const float* bout = (const float*)d_in[7];
    float* out = (float*)d_out;
    _Float16* frags = (_Float16*)d_ws;   // 301056 B used

    build_frags<<<(REGW_OFF + 3072 + 255) / 256, 256, 0, stream>>>(whh, wout, frags);
    lstm_fused_kernel<<<NSEQ / ROWS, 768, 0, stream>>>(
        obs, h0, wih, bih, bhh, bout, frags, out);
}